// Round 4
// baseline (3562.484 us; speedup 1.0000x reference)
//
#include <hip/hip_runtime.h>
#include <hip/hip_bf16.h>

// ---------------------------------------------------------------------------
// Round 3: MFMA offset convs + NHWC-bf16 everything; workspace <= 48 MiB.
//  - all features live ONCE, as padded NHWC bf16 [b][98][98][C]:
//      nh128 = concat(fr,ft) (persists; block1 conv+deform, block4 sampling)
//      F1/F2 (F3 aliases F1) written by deform kernels (borders zeroed once)
//  - offsets stored bf16 as [b][pix][72] (conv packs 4 oc / 8B store;
//    deform reads contiguous pairs)
//  - deform samples NHWC directly: each bilinear corner = one bf16x8 load
//    covering 8 channels (no fp32 NCHW copies, no per-channel gathers)
//  - no hipMemsetAsync; border zeroing via kernel
// ---------------------------------------------------------------------------

#define HH 96
#define WW 96
#define HWSZ (HH * WW)
#define BB 8
#define PW 98
#define PP (PW * PW)   // padded pixels per image

using bf16x8 = __attribute__((ext_vector_type(8))) short;
using f32x4  = __attribute__((ext_vector_type(4))) float;
using u32x4  = __attribute__((ext_vector_type(4))) unsigned int;

__device__ __forceinline__ unsigned int f2bf(float f) {
    __hip_bfloat16 h = __float2bfloat16(f);
    return (unsigned int)*reinterpret_cast<unsigned short*>(&h);
}
__device__ __forceinline__ float bflo(unsigned int u) { return __uint_as_float(u << 16); }
__device__ __forceinline__ float bfhi(unsigned int u) { return __uint_as_float(u & 0xFFFF0000u); }

// ---- weight prepack: fp32 [outC][C][3][3] -> bf16 A-frags [mt][ks][lane][8], k=t*C+c
__global__ void prepack_w_kernel(const float* __restrict__ w, short* __restrict__ wp,
                                 int outC, int C, int MT, int KS) {
    int i = blockIdx.x * 256 + threadIdx.x;
    if (i >= MT * KS * 64) return;
    int lane = i & 63;
    int s = (i >> 6) % KS;
    int m = (i >> 6) / KS;
    int oc = m * 16 + (lane & 15);
    short v[8];
#pragma unroll
    for (int j = 0; j < 8; ++j) {
        int k = s * 32 + (lane >> 4) * 8 + j;
        int t = k / C, c = k % C;
        float f = (oc < outC) ? w[((size_t)oc * C + c) * 9 + t] : 0.f;
        v[j] = (short)f2bf(f);
    }
    *reinterpret_cast<bf16x8*>(wp + (size_t)i * 8) = *reinterpret_cast<bf16x8*>(v);
}

// ---- pad+concat+convert: fr,ft fp32 NCHW -> [b][98][98][128] bf16 (full buffer)
__global__ void pad_nhwc128_kernel(const float* __restrict__ A,
                                   const float* __restrict__ B,
                                   __hip_bfloat16* __restrict__ out) {
    int i = blockIdx.x * 256 + threadIdx.x;
    if (i >= BB * PP) return;
    int px = i % PW, py = (i / PW) % PW, b = i / PP;
    unsigned int* op = reinterpret_cast<unsigned int*>(out + (size_t)i * 128);
    if (px == 0 || px == PW - 1 || py == 0 || py == PW - 1) {
#pragma unroll
        for (int c = 0; c < 64; ++c) op[c] = 0u;
        return;
    }
    const float* ap = A + (size_t)b * 64 * HWSZ + (py - 1) * WW + (px - 1);
    const float* bp = B + (size_t)b * 64 * HWSZ + (py - 1) * WW + (px - 1);
#pragma unroll 8
    for (int c = 0; c < 32; ++c)
        op[c] = f2bf(ap[(size_t)(2 * c) * HWSZ]) | (f2bf(ap[(size_t)(2 * c + 1) * HWSZ]) << 16);
#pragma unroll 8
    for (int c = 0; c < 32; ++c)
        op[32 + c] = f2bf(bp[(size_t)(2 * c) * HWSZ]) | (f2bf(bp[(size_t)(2 * c + 1) * HWSZ]) << 16);
}

// ---- zero the border ring of a [b][98][98][64] bf16 buffer
__global__ void zero_border64_kernel(__hip_bfloat16* __restrict__ p) {
    int i = blockIdx.x * 256 + threadIdx.x;
    if (i >= BB * PP) return;
    int px = i % PW, py = (i / PW) % PW;
    if (px == 0 || px == PW - 1 || py == 0 || py == PW - 1) {
        unsigned int* q = reinterpret_cast<unsigned int*>(p + (size_t)i * 64);
#pragma unroll
        for (int c = 0; c < 32; ++c) q[c] = 0u;
    }
}

// ---- MFMA implicit-GEMM 3x3 conv; out = bf16 offsets [b][pix][outC]
template <int C>
__global__ __launch_bounds__(256) void conv3_mfma_kernel(
    const __hip_bfloat16* __restrict__ xp,
    const short* __restrict__ wp,
    __hip_bfloat16* __restrict__ offb, int outC) {
    constexpr int KS = 9 * C / 32;
    int lane = threadIdx.x & 63;
    int wave = threadIdx.x >> 6;
    int y = blockIdx.x * 4 + wave;
    int m = blockIdx.y;
    int b = blockIdx.z;
    int l15 = lane & 15, lhi = lane >> 4;

    f32x4 acc[6];
#pragma unroll
    for (int nt = 0; nt < 6; ++nt) acc[nt] = (f32x4){0.f, 0.f, 0.f, 0.f};

    const short* wpm = wp + ((size_t)m * KS) * 64 * 8 + (size_t)lane * 8;

#pragma unroll 3
    for (int s = 0; s < KS; ++s) {
        bf16x8 afrag = *reinterpret_cast<const bf16x8*>(wpm + (size_t)s * 64 * 8);
        int t  = (s * 32) / C;
        int c0 = (s * 32) % C + lhi * 8;
        int ky = t / 3, kx = t % 3;
        const short* bbase = reinterpret_cast<const short*>(xp)
            + (((size_t)b * PW + (y + ky)) * PW + kx + l15) * C + c0;
#pragma unroll
        for (int nt = 0; nt < 6; ++nt) {
            bf16x8 bfrag = *reinterpret_cast<const bf16x8*>(bbase + (size_t)nt * 16 * C);
            acc[nt] = __builtin_amdgcn_mfma_f32_16x16x32_bf16(afrag, bfrag, acc[nt], 0, 0, 0);
        }
    }

    int ocb = m * 16 + lhi * 4;
    if (ocb < outC) {
#pragma unroll
        for (int nt = 0; nt < 6; ++nt) {
            int pix = y * WW + nt * 16 + l15;
            unsigned long long pk =
                  (unsigned long long)(f2bf(acc[nt][0]) | (f2bf(acc[nt][1]) << 16))
                | ((unsigned long long)(f2bf(acc[nt][2]) | (f2bf(acc[nt][3]) << 16)) << 32);
            *reinterpret_cast<unsigned long long*>(
                offb + ((size_t)b * HWSZ + pix) * outC + ocb) = pk;
        }
    }
}

// ---- deformable conv sampling NHWC bf16, offsets bf16 [b][pix][OFFC]
// CG chans/group, OCG out-chans/group, CSTR = NHWC channel stride of xp,
// CHB = channel base inside xp. FINAL: write fp32 NCHW to outp else NHWC bf16.
template <int CG, int OCG, int CSTR, int CHB, int OFFC, bool FINAL>
__global__ __launch_bounds__(256) void deform3_kernel(
    const __hip_bfloat16* __restrict__ xp,
    const __hip_bfloat16* __restrict__ offb,
    const float* __restrict__ w,
    const float* __restrict__ bias,
    __hip_bfloat16* __restrict__ onhwc,
    float* __restrict__ outp) {
    int pix = blockIdx.x * 256 + threadIdx.x;
    int g   = blockIdx.y;
    int b   = blockIdx.z;
    int x = pix % WW, y = pix / WW;

    const unsigned int* offu = reinterpret_cast<const unsigned int*>(
        offb + ((size_t)b * HWSZ + pix) * OFFC + g * 18);

    float bw0[9], bw1[9], bw2[9], bw3[9];
    int   i00[9], i01[9], i10[9], i11[9];   // element offsets (channel 0) into xp
    int rb = b * PW;
#pragma unroll
    for (int k = 0; k < 9; ++k) {
        int ky = k / 3, kx = k % 3;
        unsigned int u = offu[k];
        float offy = bflo(u), offx = bfhi(u);
        float py = offy + (float)(y - 1 + ky);
        float px = offx + (float)(x - 1 + kx);
        float fy0 = floorf(py), fx0 = floorf(px);
        float wy = py - fy0, wx = px - fx0;
        int y0 = (int)fy0, x0 = (int)fx0;
        bool vy0 = (y0 >= 0) && (y0 < HH);
        bool vy1 = (y0 + 1 >= 0) && (y0 + 1 < HH);
        bool vx0 = (x0 >= 0) && (x0 < WW);
        bool vx1 = (x0 + 1 >= 0) && (x0 + 1 < WW);
        int cy0 = min(max(y0, -1), HH - 1) + 1;       // padded coords [0,97]
        int cy1 = min(max(y0 + 1, -1), HH - 1) + 1;
        int cx0 = min(max(x0, -1), WW - 1) + 1;
        int cx1 = min(max(x0 + 1, -1), WW - 1) + 1;
        bw0[k] = (1.f - wy) * (1.f - wx) * ((vy0 && vx0) ? 1.f : 0.f);
        bw1[k] = (1.f - wy) * wx         * ((vy0 && vx1) ? 1.f : 0.f);
        bw2[k] = wy * (1.f - wx)         * ((vy1 && vx0) ? 1.f : 0.f);
        bw3[k] = wy * wx                 * ((vy1 && vx1) ? 1.f : 0.f);
        i00[k] = ((rb + cy0) * PW + cx0) * CSTR;
        i01[k] = ((rb + cy0) * PW + cx1) * CSTR;
        i10[k] = ((rb + cy1) * PW + cx0) * CSTR;
        i11[k] = ((rb + cy1) * PW + cx1) * CSTR;
    }

    float acc[OCG];
#pragma unroll
    for (int o = 0; o < OCG; ++o) acc[o] = bias[g * OCG + o];

    const float* wg = w + (size_t)g * OCG * CG * 9;      // [OCG][CG][9], uniform
    const __hip_bfloat16* xbase = xp + CHB + g * CG;

    for (int c8 = 0; c8 < CG / 8; ++c8) {
#pragma unroll
        for (int k = 0; k < 9; ++k) {
            u32x4 q00 = *reinterpret_cast<const u32x4*>(xbase + i00[k] + c8 * 8);
            u32x4 q01 = *reinterpret_cast<const u32x4*>(xbase + i01[k] + c8 * 8);
            u32x4 q10 = *reinterpret_cast<const u32x4*>(xbase + i10[k] + c8 * 8);
            u32x4 q11 = *reinterpret_cast<const u32x4*>(xbase + i11[k] + c8 * 8);
#pragma unroll
            for (int j = 0; j < 4; ++j) {
                float vlo = bw0[k] * bflo(q00[j]) + bw1[k] * bflo(q01[j])
                          + bw2[k] * bflo(q10[j]) + bw3[k] * bflo(q11[j]);
                float vhi = bw0[k] * bfhi(q00[j]) + bw1[k] * bfhi(q01[j])
                          + bw2[k] * bfhi(q10[j]) + bw3[k] * bfhi(q11[j]);
                int c = c8 * 8 + 2 * j;
                const float* wck = wg + (size_t)c * 9 + k;
#pragma unroll
                for (int o = 0; o < OCG; ++o) {
                    acc[o] += vlo * wck[(size_t)o * CG * 9];
                    acc[o] += vhi * wck[(size_t)o * CG * 9 + 9];
                }
            }
        }
    }

    if (!FINAL) {
        unsigned int* q = reinterpret_cast<unsigned int*>(
            onhwc + (((size_t)rb + (y + 1)) * PW + (x + 1)) * 64 + g * OCG);
#pragma unroll
        for (int o = 0; o < OCG / 2; ++o)
            q[o] = f2bf(acc[2 * o]) | (f2bf(acc[2 * o + 1]) << 16);
    } else {
        float* op = outp + ((size_t)b * 64 + g * OCG) * HWSZ + pix;
#pragma unroll
        for (int o = 0; o < OCG; ++o) op[(size_t)o * HWSZ] = acc[o];
    }
}

extern "C" void kernel_launch(void* const* d_in, const int* in_sizes, int n_in,
                              void* d_out, int out_size, void* d_ws, size_t ws_size,
                              hipStream_t stream) {
    const float* fr     = (const float*)d_in[0];
    const float* ft     = (const float*)d_in[1];
    const float* off1_w = (const float*)d_in[2];
    const float* def1_w = (const float*)d_in[3];
    const float* def1_b = (const float*)d_in[4];
    const float* off2_w = (const float*)d_in[5];
    const float* def2_w = (const float*)d_in[6];
    const float* def2_b = (const float*)d_in[7];
    const float* off3_w = (const float*)d_in[8];
    const float* def3_w = (const float*)d_in[9];
    const float* def3_b = (const float*)d_in[10];
    const float* off4_w = (const float*)d_in[11];
    const float* def4_w = (const float*)d_in[12];
    const float* def4_b = (const float*)d_in[13];
    float* outp = (float*)d_out;

    // ---- workspace layout (total ~48.0 MiB) ----
    char* ws = (char*)d_ws;
    __hip_bfloat16* offb  = (__hip_bfloat16*)ws; ws += (size_t)BB * HWSZ * 72 * 2;  // 10.6 MB
    __hip_bfloat16* nh128 = (__hip_bfloat16*)ws; ws += (size_t)BB * PP * 128 * 2;   // 19.7 MB
    __hip_bfloat16* F1    = (__hip_bfloat16*)ws; ws += (size_t)BB * PP * 64 * 2;    // 9.8 MB
    __hip_bfloat16* F2    = (__hip_bfloat16*)ws; ws += (size_t)BB * PP * 64 * 2;    // 9.8 MB
    short* wp1 = (short*)ws; ws += (size_t)5 * 36 * 64 * 8 * 2;
    short* wp2 = (short*)ws; ws += (size_t)5 * 18 * 64 * 8 * 2;
    short* wp3 = (short*)ws; ws += (size_t)5 * 18 * 64 * 8 * 2;
    short* wp4 = (short*)ws; ws += (size_t)3 * 18 * 64 * 8 * 2;
    __hip_bfloat16* F3 = F1;   // F1 dead after block-2 deform

    dim3 blk(256);
    int padBlocks = (BB * PP + 255) / 256;

    prepack_w_kernel<<<(5 * 36 * 64 + 255) / 256, blk, 0, stream>>>(off1_w, wp1, 72, 128, 5, 36);
    prepack_w_kernel<<<(5 * 18 * 64 + 255) / 256, blk, 0, stream>>>(off2_w, wp2, 72, 64, 5, 18);
    prepack_w_kernel<<<(5 * 18 * 64 + 255) / 256, blk, 0, stream>>>(off3_w, wp3, 72, 64, 5, 18);
    prepack_w_kernel<<<(3 * 18 * 64 + 255) / 256, blk, 0, stream>>>(off4_w, wp4, 36, 64, 3, 18);

    zero_border64_kernel<<<padBlocks, blk, 0, stream>>>(F1);
    zero_border64_kernel<<<padBlocks, blk, 0, stream>>>(F2);
    pad_nhwc128_kernel<<<padBlocks, blk, 0, stream>>>(fr, ft, nh128);

    dim3 gDefG4(36, 4, BB), gDefG2(36, 2, BB);

    // ---- block 1: conv(128ch)->72 offsets; deform on nh128 (G=4,Cg=32,outCg=16)
    conv3_mfma_kernel<128><<<dim3(24, 5, BB), blk, 0, stream>>>(nh128, wp1, offb, 72);
    deform3_kernel<32, 16, 128, 0, 72, false><<<gDefG4, blk, 0, stream>>>(
        nh128, offb, def1_w, def1_b, F1, nullptr);

    // ---- block 2: conv(F1)->72; deform on F1 (G=4,Cg=16,outCg=16) -> F2
    conv3_mfma_kernel<64><<<dim3(24, 5, BB), blk, 0, stream>>>(F1, wp2, offb, 72);
    deform3_kernel<16, 16, 64, 0, 72, false><<<gDefG4, blk, 0, stream>>>(
        F1, offb, def2_w, def2_b, F2, nullptr);

    // ---- block 3: conv(F2)->72; deform on F2 -> F3 (=F1)
    conv3_mfma_kernel<64><<<dim3(24, 5, BB), blk, 0, stream>>>(F2, wp3, offb, 72);
    deform3_kernel<16, 16, 64, 0, 72, false><<<gDefG4, blk, 0, stream>>>(
        F2, offb, def3_w, def3_b, F3, nullptr);

    // ---- block 4: conv(F3)->36; deform samples ft = nh128 chans 64..127 (G=2)
    conv3_mfma_kernel<64><<<dim3(24, 3, BB), blk, 0, stream>>>(F3, wp4, offb, 36);
    deform3_kernel<32, 32, 128, 64, 36, true><<<gDefG2, blk, 0, stream>>>(
        nh128, offb, def4_w, def4_b, nullptr, outp);
}

// Round 5
// 1101.453 us; speedup vs baseline: 3.2344x; 3.2344x over previous
//
#include <hip/hip_runtime.h>
#include <hip/hip_bf16.h>

// ---------------------------------------------------------------------------
// Round 4: two-layout design, <= ~50 MiB workspace.
//  - conv (MFMA implicit GEMM) consumes padded NHWC bf16 [b][98][98][64],
//    writes offsets as bf16 NCHW planes (coalesced for deform).
//  - deform samples NCHW planes (fp32 inputs or bf16 copies): consecutive
//    lanes = consecutive x -> coalesced corner gathers (round-1 structure).
//    Dual-store: NCHW bf16 (next deform src) + NHWC bf16 (next conv src).
//  - buffer aliasing: P0=frn/F2, P1=ftn/A2, P2=F1/F3, P3=A1.
// ---------------------------------------------------------------------------

#define HH 96
#define WW 96
#define HWSZ (HH * WW)
#define BB 8
#define PW 98
#define PP (PW * PW)

using bf16x8 = __attribute__((ext_vector_type(8))) short;
using f32x4  = __attribute__((ext_vector_type(4))) float;

__device__ __forceinline__ unsigned int f2bf(float f) {
    __hip_bfloat16 h = __float2bfloat16(f);
    return (unsigned int)*reinterpret_cast<unsigned short*>(&h);
}
__device__ __forceinline__ float bf2f(unsigned short u) {
    return __uint_as_float(((unsigned int)u) << 16);
}

// ---- weight prepack: fp32 [outC][C][3][3] -> bf16 A-frags [mt][ks][lane][8], k=t*C+c
__global__ void prepack_w_kernel(const float* __restrict__ w, short* __restrict__ wp,
                                 int outC, int C, int MT, int KS) {
    int i = blockIdx.x * 256 + threadIdx.x;
    if (i >= MT * KS * 64) return;
    int lane = i & 63;
    int s = (i >> 6) % KS;
    int m = (i >> 6) / KS;
    int oc = m * 16 + (lane & 15);
    short v[8];
#pragma unroll
    for (int j = 0; j < 8; ++j) {
        int k = s * 32 + (lane >> 4) * 8 + j;
        int t = k / C, c = k % C;
        float f = (oc < outC) ? w[((size_t)oc * C + c) * 9 + t] : 0.f;
        v[j] = (short)f2bf(f);
    }
    *reinterpret_cast<bf16x8*>(wp + (size_t)i * 8) = *reinterpret_cast<bf16x8*>(v);
}

// ---- pad one fp32 NCHW 64-ch tensor -> [b][98][98][64] bf16 (borders zeroed)
__global__ void pad_nhwc64_kernel(const float* __restrict__ src,
                                  __hip_bfloat16* __restrict__ out) {
    int i = blockIdx.x * 256 + threadIdx.x;
    if (i >= BB * PP) return;
    int px = i % PW, py = (i / PW) % PW, b = i / PP;
    unsigned int* op = reinterpret_cast<unsigned int*>(out + (size_t)i * 64);
    if (px == 0 || px == PW - 1 || py == 0 || py == PW - 1) {
#pragma unroll
        for (int c = 0; c < 32; ++c) op[c] = 0u;
        return;
    }
    const float* sp = src + (size_t)b * 64 * HWSZ + (py - 1) * WW + (px - 1);
#pragma unroll 8
    for (int c = 0; c < 32; ++c)
        op[c] = f2bf(sp[(size_t)(2 * c) * HWSZ]) | (f2bf(sp[(size_t)(2 * c + 1) * HWSZ]) << 16);
}

// ---- zero the border ring of a [b][98][98][64] bf16 buffer
__global__ void zero_border64_kernel(__hip_bfloat16* __restrict__ p) {
    int i = blockIdx.x * 256 + threadIdx.x;
    if (i >= BB * PP) return;
    int px = i % PW, py = (i / PW) % PW;
    if (px == 0 || px == PW - 1 || py == 0 || py == PW - 1) {
        unsigned int* q = reinterpret_cast<unsigned int*>(p + (size_t)i * 64);
#pragma unroll
        for (int c = 0; c < 32; ++c) q[c] = 0u;
    }
}

// ---- MFMA implicit-GEMM 3x3 conv; out = bf16 NCHW offset planes
// xa: channels 0..63, xb: channels 64..127 (same pointer for C=64).
template <int C>
__global__ __launch_bounds__(256) void conv3_mfma_kernel(
    const __hip_bfloat16* __restrict__ xa,
    const __hip_bfloat16* __restrict__ xb,
    const short* __restrict__ wp,
    __hip_bfloat16* __restrict__ offb, int outC) {
    constexpr int KS = 9 * C / 32;
    int lane = threadIdx.x & 63;
    int wave = threadIdx.x >> 6;
    int y = blockIdx.x * 4 + wave;
    int m = blockIdx.y;
    int b = blockIdx.z;
    int l15 = lane & 15, lhi = lane >> 4;

    f32x4 acc[6];
#pragma unroll
    for (int nt = 0; nt < 6; ++nt) acc[nt] = (f32x4){0.f, 0.f, 0.f, 0.f};

    const short* wpm = wp + ((size_t)m * KS) * 64 * 8 + (size_t)lane * 8;

#pragma unroll 3
    for (int s = 0; s < KS; ++s) {
        bf16x8 afrag = *reinterpret_cast<const bf16x8*>(wpm + (size_t)s * 64 * 8);
        int t  = (s * 32) / C;
        int cb = (s * 32) % C;
        const __hip_bfloat16* xp = (cb < 64) ? xa : xb;
        int c0 = (cb & 63) + lhi * 8;
        int ky = t / 3, kx = t % 3;
        const short* bbase = reinterpret_cast<const short*>(xp)
            + (((size_t)b * PW + (y + ky)) * PW + kx + l15) * 64 + c0;
#pragma unroll
        for (int nt = 0; nt < 6; ++nt) {
            bf16x8 bfrag = *reinterpret_cast<const bf16x8*>(bbase + (size_t)nt * 16 * 64);
            acc[nt] = __builtin_amdgcn_mfma_f32_16x16x32_bf16(afrag, bfrag, acc[nt], 0, 0, 0);
        }
    }

    int ocb = m * 16 + lhi * 4;
#pragma unroll
    for (int nt = 0; nt < 6; ++nt) {
        int pix = y * WW + nt * 16 + l15;
#pragma unroll
        for (int r = 0; r < 4; ++r) {
            int oc = ocb + r;
            if (oc < outC) {
                unsigned short hv = (unsigned short)f2bf(acc[nt][r]);
                *reinterpret_cast<unsigned short*>(
                    offb + ((size_t)b * outC + oc) * HWSZ + pix) = hv;
            }
        }
    }
}

// ---- deformable conv: NCHW-plane sampling (coalesced), round-1 structure ---
// xA: channels 0..63, xB: 64..127 (same pointer when single tensor).
// offb: bf16 NCHW [b][OFFC][HW]. Outputs optional via template bools.
template <int CG, int OCG, int OFFC, bool SRCBF, bool HASN, bool HASH, bool FINAL>
__global__ __launch_bounds__(256) void deform4_kernel(
    const void* __restrict__ xA, const void* __restrict__ xB,
    const __hip_bfloat16* __restrict__ offb,
    const float* __restrict__ w,
    const float* __restrict__ bias,
    __hip_bfloat16* __restrict__ anchw,
    __hip_bfloat16* __restrict__ fnhwc,
    float* __restrict__ outp) {
    int pix = blockIdx.x * 256 + threadIdx.x;
    int g   = blockIdx.y;
    int b   = blockIdx.z;
    int x = pix % WW, y = pix / WW;

    const __hip_bfloat16* ob = offb + ((size_t)b * OFFC + g * 18) * HWSZ + pix;

    float bw0[9], bw1[9], bw2[9], bw3[9];
    int   bi0[9], bi1[9], bi2[9], bi3[9];
#pragma unroll
    for (int k = 0; k < 9; ++k) {
        int ky = k / 3, kx = k % 3;
        float offy = bf2f(*reinterpret_cast<const unsigned short*>(ob + (size_t)(2 * k) * HWSZ));
        float offx = bf2f(*reinterpret_cast<const unsigned short*>(ob + (size_t)(2 * k + 1) * HWSZ));
        float py = offy + (float)(y - 1 + ky);
        float px = offx + (float)(x - 1 + kx);
        float fy0 = floorf(py), fx0 = floorf(px);
        float wy = py - fy0, wx = px - fx0;
        int y0 = (int)fy0, x0 = (int)fx0;
        int y1 = y0 + 1,  x1 = x0 + 1;
        bool vy0 = (y0 >= 0) && (y0 < HH);
        bool vy1 = (y1 >= 0) && (y1 < HH);
        bool vx0 = (x0 >= 0) && (x0 < WW);
        bool vx1 = (x1 >= 0) && (x1 < WW);
        int cy0 = min(max(y0, 0), HH - 1), cy1 = min(max(y1, 0), HH - 1);
        int cx0 = min(max(x0, 0), WW - 1), cx1 = min(max(x1, 0), WW - 1);
        bw0[k] = (1.f - wy) * (1.f - wx) * ((vy0 && vx0) ? 1.f : 0.f);
        bw1[k] = (1.f - wy) * wx         * ((vy0 && vx1) ? 1.f : 0.f);
        bw2[k] = wy * (1.f - wx)         * ((vy1 && vx0) ? 1.f : 0.f);
        bw3[k] = wy * wx                 * ((vy1 && vx1) ? 1.f : 0.f);
        bi0[k] = cy0 * WW + cx0;  bi1[k] = cy0 * WW + cx1;
        bi2[k] = cy1 * WW + cx0;  bi3[k] = cy1 * WW + cx1;
    }

    float acc[OCG];
#pragma unroll
    for (int o = 0; o < OCG; ++o) acc[o] = bias[g * OCG + o];

    int gc = g * CG;
    const void* srcv = (gc < 64) ? xA : xB;
    size_t pbase = (size_t)b * 64 + (size_t)((gc < 64) ? gc : gc - 64);

    for (int c = 0; c < CG; ++c) {
        float v[9];
        if constexpr (SRCBF) {
            const unsigned short* p = (const unsigned short*)srcv + (pbase + c) * HWSZ;
#pragma unroll
            for (int k = 0; k < 9; ++k)
                v[k] = bw0[k] * bf2f(p[bi0[k]]) + bw1[k] * bf2f(p[bi1[k]])
                     + bw2[k] * bf2f(p[bi2[k]]) + bw3[k] * bf2f(p[bi3[k]]);
        } else {
            const float* p = (const float*)srcv + (pbase + c) * HWSZ;
#pragma unroll
            for (int k = 0; k < 9; ++k)
                v[k] = bw0[k] * p[bi0[k]] + bw1[k] * p[bi1[k]]
                     + bw2[k] * p[bi2[k]] + bw3[k] * p[bi3[k]];
        }
        const float* wc = w + ((size_t)(g * OCG) * CG + c) * 9;
#pragma unroll
        for (int o = 0; o < OCG; ++o) {
            const float* wo = wc + (size_t)o * CG * 9;
#pragma unroll
            for (int k = 0; k < 9; ++k) acc[o] = fmaf(v[k], wo[k], acc[o]);
        }
    }

    if constexpr (HASN) {
#pragma unroll
        for (int o = 0; o < OCG; ++o)
            *reinterpret_cast<unsigned short*>(
                anchw + ((size_t)b * 64 + g * OCG + o) * HWSZ + pix) =
                (unsigned short)f2bf(acc[o]);
    }
    if constexpr (HASH) {
        unsigned int* q = reinterpret_cast<unsigned int*>(
            fnhwc + (((size_t)b * PW + (y + 1)) * PW + (x + 1)) * 64 + g * OCG);
#pragma unroll
        for (int o = 0; o < OCG / 2; ++o)
            q[o] = f2bf(acc[2 * o]) | (f2bf(acc[2 * o + 1]) << 16);
    }
    if constexpr (FINAL) {
        float* op = outp + ((size_t)b * 64 + g * OCG) * HWSZ + pix;
#pragma unroll
        for (int o = 0; o < OCG; ++o) op[(size_t)o * HWSZ] = acc[o];
    }
}

extern "C" void kernel_launch(void* const* d_in, const int* in_sizes, int n_in,
                              void* d_out, int out_size, void* d_ws, size_t ws_size,
                              hipStream_t stream) {
    const float* fr     = (const float*)d_in[0];
    const float* ft     = (const float*)d_in[1];
    const float* off1_w = (const float*)d_in[2];
    const float* def1_w = (const float*)d_in[3];
    const float* def1_b = (const float*)d_in[4];
    const float* off2_w = (const float*)d_in[5];
    const float* def2_w = (const float*)d_in[6];
    const float* def2_b = (const float*)d_in[7];
    const float* off3_w = (const float*)d_in[8];
    const float* def3_w = (const float*)d_in[9];
    const float* def3_b = (const float*)d_in[10];
    const float* off4_w = (const float*)d_in[11];
    const float* def4_w = (const float*)d_in[12];
    const float* def4_b = (const float*)d_in[13];
    float* outp = (float*)d_out;

    // ---- workspace layout (~50.4 MiB total) ----
    char* ws = (char*)d_ws;
    const size_t offb_sz = (size_t)BB * 72 * HWSZ * 2;   // 10.6 MB
    const size_t pbuf_sz = (size_t)BB * PP * 64 * 2;     //  9.8 MB each
    __hip_bfloat16* offb = (__hip_bfloat16*)ws; ws += offb_sz;
    __hip_bfloat16* P0   = (__hip_bfloat16*)ws; ws += pbuf_sz;  // frn, later F2
    __hip_bfloat16* P1   = (__hip_bfloat16*)ws; ws += pbuf_sz;  // ftn, later A2 (NCHW)
    __hip_bfloat16* P2   = (__hip_bfloat16*)ws; ws += pbuf_sz;  // F1, later F3
    __hip_bfloat16* P3   = (__hip_bfloat16*)ws; ws += pbuf_sz;  // A1 (NCHW)
    short* wp1 = (short*)ws; ws += (size_t)5 * 36 * 64 * 8 * 2;
    short* wp2 = (short*)ws; ws += (size_t)5 * 18 * 64 * 8 * 2;
    short* wp3 = (short*)ws; ws += (size_t)5 * 18 * 64 * 8 * 2;
    short* wp4 = (short*)ws; ws += (size_t)3 * 18 * 64 * 8 * 2;

    dim3 blk(256);
    int padBlocks = (BB * PP + 255) / 256;

    prepack_w_kernel<<<(5 * 36 * 64 + 255) / 256, blk, 0, stream>>>(off1_w, wp1, 72, 128, 5, 36);
    prepack_w_kernel<<<(5 * 18 * 64 + 255) / 256, blk, 0, stream>>>(off2_w, wp2, 72, 64, 5, 18);
    prepack_w_kernel<<<(5 * 18 * 64 + 255) / 256, blk, 0, stream>>>(off3_w, wp3, 72, 64, 5, 18);
    prepack_w_kernel<<<(3 * 18 * 64 + 255) / 256, blk, 0, stream>>>(off4_w, wp4, 36, 64, 3, 18);

    pad_nhwc64_kernel<<<padBlocks, blk, 0, stream>>>(fr, P0);
    pad_nhwc64_kernel<<<padBlocks, blk, 0, stream>>>(ft, P1);
    zero_border64_kernel<<<padBlocks, blk, 0, stream>>>(P2);

    dim3 gDefG4(36, 4, BB), gDefG2(36, 2, BB);

    // ---- block 1: conv(concat via dual ptr) -> 72 offsets; deform on fr/ft fp32
    conv3_mfma_kernel<128><<<dim3(24, 5, BB), blk, 0, stream>>>(P0, P1, wp1, offb, 72);
    deform4_kernel<32, 16, 72, false, true, true, false><<<gDefG4, blk, 0, stream>>>(
        fr, ft, offb, def1_w, def1_b, P3 /*A1*/, P2 /*F1*/, nullptr);

    // ---- block 2: conv(F1) -> offsets; deform samples A1 -> A2(P1) + F2(P0)
    conv3_mfma_kernel<64><<<dim3(24, 5, BB), blk, 0, stream>>>(P2, P2, wp2, offb, 72);
    deform4_kernel<16, 16, 72, true, true, true, false><<<gDefG4, blk, 0, stream>>>(
        P3, P3, offb, def2_w, def2_b, P1 /*A2*/, P0 /*F2*/, nullptr);

    // ---- block 3: conv(F2) -> offsets; deform samples A2 -> F3(P2) only
    conv3_mfma_kernel<64><<<dim3(24, 5, BB), blk, 0, stream>>>(P0, P0, wp3, offb, 72);
    deform4_kernel<16, 16, 72, true, false, true, false><<<gDefG4, blk, 0, stream>>>(
        P1, P1, offb, def3_w, def3_b, nullptr, P2 /*F3*/, nullptr);

    // ---- block 4: conv(F3) -> 36 offsets; deform samples ft fp32 -> output
    conv3_mfma_kernel<64><<<dim3(24, 3, BB), blk, 0, stream>>>(P2, P2, wp4, offb, 36);
    deform4_kernel<32, 32, 36, false, false, false, true><<<gDefG2, blk, 0, stream>>>(
        ft, ft, offb, def4_w, def4_b, nullptr, nullptr, outp);
}